// Round 1
// baseline (140.576 us; speedup 1.0000x reference)
//
#include <hip/hip_runtime.h>
#include <hip/hip_bf16.h>

#define N_PTS 131072
#define RES_A 128
#define RES_B 256

// Transposed grids: gt[axis][i][d*8+c], row of 128 floats per sample index i.
__device__ float g_gta[3 * RES_A * 128];
__device__ float g_gtb[3 * RES_B * 128];

__global__ __launch_bounds__(256) void transpose_kernel(
    const float* __restrict__ g0a, const float* __restrict__ g1a, const float* __restrict__ g2a,
    const float* __restrict__ g0b, const float* __restrict__ g1b, const float* __restrict__ g2b) {
  int tid = blockIdx.x * 256 + threadIdx.x;
  if (tid < 3 * RES_A * 128) {
    int axis = tid / (RES_A * 128);
    int rem = tid - axis * (RES_A * 128);
    int i = rem >> 7;        // sample index 0..127
    int dc = rem & 127;      // d*8+c
    const float* src = axis == 0 ? g0a : (axis == 1 ? g1a : g2a);
    g_gta[tid] = src[dc * RES_A + i];
  } else {
    int t = tid - 3 * RES_A * 128;
    if (t < 3 * RES_B * 128) {
      int axis = t / (RES_B * 128);
      int rem = t - axis * (RES_B * 128);
      int i = rem >> 7;      // 0..255
      int dc = rem & 127;
      const float* src = axis == 0 ? g0b : (axis == 1 ? g1b : g2b);
      g_gtb[t] = src[dc * RES_B + i];
    }
  }
}

__device__ __forceinline__ void lerp8(const float* __restrict__ row0,
                                      const float* __restrict__ row1,
                                      float w, float* dst) {
#pragma unroll
  for (int j = 0; j < 8; j += 4) {
    float4 a = *(const float4*)(row0 + j);
    float4 b = *(const float4*)(row1 + j);
    dst[j + 0] = fmaf(w, b.x - a.x, a.x);
    dst[j + 1] = fmaf(w, b.y - a.y, a.y);
    dst[j + 2] = fmaf(w, b.z - a.z, a.z);
    dst[j + 3] = fmaf(w, b.w - a.w, a.w);
  }
}

// One thread per (point n, output dim d). blockIdx.y = scale (wave-uniform so
// the core tensor reads become scalar s_loads).
__global__ __launch_bounds__(256) void tucker_kernel(
    const float* __restrict__ pts,
    const float* __restrict__ corea,
    const float* __restrict__ coreb,
    float* __restrict__ out) {
  const int scale = blockIdx.y;
  const int d  = threadIdx.x & 15;
  const int nl = threadIdx.x >> 4;
  const int n  = blockIdx.x * 16 + nl;

  const int r = scale ? RES_B : RES_A;
  const float* __restrict__ C  = scale ? coreb : corea;
  const float* __restrict__ gt = scale ? g_gtb : g_gta;
  const int axis_stride = r * 128;
  const float half_rm1 = 0.5f * (float)(r - 1);

  const float px = pts[n * 3 + 0];
  const float py = pts[n * 3 + 1];
  const float pz = pts[n * 3 + 2];

  float ax[8], ay[8], az[8];

#pragma unroll
  for (int axis = 0; axis < 3; ++axis) {
    float c = (axis == 0) ? px : ((axis == 1) ? py : pz);
    float pos = (c + 1.0f) * half_rm1;
    pos = fminf(fmaxf(pos, 0.0f), (float)(r - 1));
    int i0 = (int)floorf(pos);
    int i1 = min(i0 + 1, r - 1);
    float w = pos - (float)i0;
    const float* row0 = gt + axis * axis_stride + i0 * 128 + d * 8;
    const float* row1 = gt + axis * axis_stride + i1 * 128 + d * 8;
    float* dst = (axis == 0) ? ax : ((axis == 1) ? ay : az);
    lerp8(row0, row1, w, dst);
  }

  // out = sum_x ax[x] * sum_y ay[y] * sum_z C[x][y][z] * az[z]
  float acc = 0.0f;
#pragma unroll
  for (int x = 0; x < 8; ++x) {
    float vx = 0.0f;
#pragma unroll
    for (int y = 0; y < 8; ++y) {
      float s = 0.0f;
#pragma unroll
      for (int z = 0; z < 8; ++z)
        s = fmaf(C[(x * 8 + y) * 8 + z], az[z], s);
      vx = fmaf(s, ay[y], vx);
    }
    acc = fmaf(vx, ax[x], acc);
  }

  out[n * 32 + scale * 16 + d] = acc;
}

extern "C" void kernel_launch(void* const* d_in, const int* in_sizes, int n_in,
                              void* d_out, int out_size, void* d_ws, size_t ws_size,
                              hipStream_t stream) {
  const float* pts   = (const float*)d_in[0];
  const float* g0a   = (const float*)d_in[1];
  const float* g1a   = (const float*)d_in[2];
  const float* g2a   = (const float*)d_in[3];
  const float* corea = (const float*)d_in[4];
  const float* g0b   = (const float*)d_in[5];
  const float* g1b   = (const float*)d_in[6];
  const float* g2b   = (const float*)d_in[7];
  const float* coreb = (const float*)d_in[8];
  float* out = (float*)d_out;

  // 147456 transposed elements total -> exactly 576 blocks of 256.
  transpose_kernel<<<576, 256, 0, stream>>>(g0a, g1a, g2a, g0b, g1b, g2b);

  dim3 grid(N_PTS / 16, 2);
  tucker_kernel<<<grid, 256, 0, stream>>>(pts, corea, coreb, out);
}